// Round 1
// baseline (389.894 us; speedup 1.0000x reference)
//
#include <hip/hip_runtime.h>

#define MARGIN 0.2f
#define EPSC 1e-6f
#define INF_I 0x7fffffff

// -------- Kernel 1: triplet mining (single block) --------
// Computes pos_idx / neg_idx / valid per row using first/second-occurrence
// tables per label instead of the B x B mask. Also zero-inits the global
// accumulators used by the distance kernel (d_ws is poisoned to 0xAA).
__global__ __launch_bounds__(1024) void mine_kernel(
    const int* __restrict__ label, const int* __restrict__ zidx, int B,
    int* __restrict__ g_pos, int* __restrict__ g_neg, int* __restrict__ g_valid,
    float* __restrict__ g_sum, int* __restrict__ g_cnt, unsigned* __restrict__ g_done)
{
    __shared__ int s_label[8192];        // B <= 8192 (setup: B = 8192)
    __shared__ int s_first[258];         // labels in [-1, 256] -> index l+1
    __shared__ int s_second[258];
    __shared__ int s_fd_orig;            // first j with label[j] != label[0] (orig labels)
    __shared__ int s_fd_eff;             // same, on effective labels
    const int tid = threadIdx.x;
    const int T   = blockDim.x;

    if (tid < 258) { s_first[tid] = INF_I; s_second[tid] = INF_I; }
    if (tid == 0) {
        s_fd_orig = INF_I; s_fd_eff = INF_I;
        *g_sum = 0.0f; *g_cnt = 0; *g_done = 0u;
    }
    for (int j = tid; j < B; j += T) s_label[j] = label[j];
    __syncthreads();

    // first difference on ORIGINAL labels -> all_same check
    const int l0 = s_label[0];
    int lm = INF_I;
    for (int j = tid; j < B; j += T) { if (s_label[j] != l0) { lm = j; break; } }
    if (lm != INF_I) atomicMin(&s_fd_orig, lm);
    __syncthreads();

    const bool all_same = (s_fd_orig == INF_I);
    int k = B / 100; if (k < 2) k = 2;   // int(B*0.01), B=8192 -> 81
    if (all_same) { for (int j = tid; j < k && j < B; j += T) s_label[j] = -1; }
    __syncthreads();

    // first occurrence per label + first difference on EFFECTIVE labels
    const int l0e = s_label[0];
    lm = INF_I;
    for (int j = tid; j < B; j += T) {
        int l = s_label[j];
        atomicMin(&s_first[l + 1], j);
        if (l != l0e && j < lm) lm = j;
    }
    if (lm != INF_I) atomicMin(&s_fd_eff, lm);
    __syncthreads();

    // second occurrence per label
    for (int j = tid; j < B; j += T) {
        int l = s_label[j];
        if (j != s_first[l + 1]) atomicMin(&s_second[l + 1], j);
    }
    __syncthreads();

    const int fd = s_fd_eff;
    for (int i = tid; i < B; i += T) {
        int l  = s_label[i];
        int fo = s_first[l + 1];         // always valid: i itself has label l
        int myidx = zidx[i];
        int pos; bool vp;
        if (zidx[fo] != myidx) { pos = fo; vp = true; }
        else {
            int so = s_second[l + 1];
            if (so != INF_I) { pos = so; vp = true; }
            else             { pos = 0;  vp = false; }  // argmax of all-False row = 0
        }
        int neg; bool vn;
        if (l != l0e)        { neg = 0;  vn = true; }
        else if (fd != INF_I){ neg = fd; vn = true; }
        else                 { neg = 0;  vn = false; }
        g_pos[i] = pos; g_neg[i] = neg; g_valid[i] = (vp && vn) ? 1 : 0;
    }
}

// -------- Kernel 2: distances + masked mean (one block per row) --------
__global__ __launch_bounds__(256) void dist_kernel(
    const float* __restrict__ z, const int* __restrict__ g_pos,
    const int* __restrict__ g_neg, const int* __restrict__ g_valid,
    int C, float* __restrict__ g_sum, int* __restrict__ g_cnt,
    unsigned* __restrict__ g_done, float* __restrict__ out)
{
    const int i = blockIdx.x;
    const int t = threadIdx.x;
    const float* a = z + (size_t)i * C;
    const float* p = z + (size_t)g_pos[i] * C;
    const float* n = z + (size_t)g_neg[i] * C;

    float sap = 0.f, san = 0.f;
    for (int c = t * 4; c < C; c += blockDim.x * 4) {
        float4 av = *(const float4*)(a + c);
        float4 pv = *(const float4*)(p + c);
        float4 nv = *(const float4*)(n + c);
        float d;
        d = av.x - pv.x + EPSC; sap += d * d;
        d = av.y - pv.y + EPSC; sap += d * d;
        d = av.z - pv.z + EPSC; sap += d * d;
        d = av.w - pv.w + EPSC; sap += d * d;
        d = av.x - nv.x + EPSC; san += d * d;
        d = av.y - nv.y + EPSC; san += d * d;
        d = av.z - nv.z + EPSC; san += d * d;
        d = av.w - nv.w + EPSC; san += d * d;
    }
    // wave (64-lane) shuffle reduce
    for (int off = 32; off > 0; off >>= 1) {
        sap += __shfl_down(sap, off, 64);
        san += __shfl_down(san, off, 64);
    }
    __shared__ float s_ap[4], s_an[4];
    const int wave = t >> 6, lane = t & 63;
    if (lane == 0) { s_ap[wave] = sap; s_an[wave] = san; }
    __syncthreads();

    if (t == 0) {
        float tap = 0.f, tn = 0.f;
        const int nw = (blockDim.x + 63) >> 6;
        for (int w = 0; w < nw; ++w) { tap += s_ap[w]; tn += s_an[w]; }
        float per = fmaxf(sqrtf(tap) - sqrtf(tn) + MARGIN, 0.f);
        if (g_valid[i]) { atomicAdd(g_sum, per); atomicAdd(g_cnt, 1); }
        __threadfence();
        unsigned done = atomicAdd(g_done, 1u);
        if (done == gridDim.x - 1) {           // last block finalizes
            float s  = atomicAdd(g_sum, 0.0f); // coherent read
            int  cnt = atomicAdd(g_cnt, 0);
            out[0] = (cnt > 0) ? s / (float)cnt : 0.0f;
        }
    }
}

extern "C" void kernel_launch(void* const* d_in, const int* in_sizes, int n_in,
                              void* d_out, int out_size, void* d_ws, size_t ws_size,
                              hipStream_t stream) {
    const int*   z_label = (const int*)d_in[0];
    const int*   z_idx   = (const int*)d_in[1];
    const float* z       = (const float*)d_in[2];
    const int B = in_sizes[0];
    const int C = in_sizes[2] / B;
    float* out = (float*)d_out;

    char* base = (char*)d_ws;
    float*    g_sum  = (float*)base;
    int*      g_cnt  = (int*)(base + 4);
    unsigned* g_done = (unsigned*)(base + 8);
    int* g_pos   = (int*)(base + 16);
    int* g_neg   = g_pos + B;
    int* g_valid = g_neg + B;

    mine_kernel<<<1, 1024, 0, stream>>>(z_label, z_idx, B,
                                        g_pos, g_neg, g_valid,
                                        g_sum, g_cnt, g_done);
    dist_kernel<<<B, 256, 0, stream>>>(z, g_pos, g_neg, g_valid, C,
                                       g_sum, g_cnt, g_done, out);
}

// Round 2
// 98.916 us; speedup vs baseline: 3.9417x; 3.9417x over previous
//
#include <hip/hip_runtime.h>

#define MARGIN 0.2f
#define EPSC 1e-6f
#define INF_I 0x7fffffff
#define NB 1024   // dist grid size (partial-sum slots)

// -------- Kernel 1: triplet mining (single block) --------
// first/second-occurrence tables per label instead of the B x B mask.
__global__ __launch_bounds__(1024) void mine_kernel(
    const int* __restrict__ label, const int* __restrict__ zidx, int B,
    int* __restrict__ g_pos, int* __restrict__ g_neg, int* __restrict__ g_valid)
{
    __shared__ int s_label[8192];        // B <= 8192
    __shared__ int s_first[258];         // labels in [-1, 256] -> index l+1
    __shared__ int s_second[258];
    __shared__ int s_fd_orig;            // first j with label[j] != label[0] (orig)
    __shared__ int s_fd_eff;             // same, effective labels
    const int tid = threadIdx.x;
    const int T   = blockDim.x;

    if (tid < 258) { s_first[tid] = INF_I; s_second[tid] = INF_I; }
    if (tid == 0) { s_fd_orig = INF_I; s_fd_eff = INF_I; }
    for (int j = tid; j < B; j += T) s_label[j] = label[j];
    __syncthreads();

    const int l0 = s_label[0];
    int lm = INF_I;
    for (int j = tid; j < B; j += T) { if (s_label[j] != l0) { lm = j; break; } }
    if (lm != INF_I) atomicMin(&s_fd_orig, lm);
    __syncthreads();

    const bool all_same = (s_fd_orig == INF_I);
    int k = B / 100; if (k < 2) k = 2;
    if (all_same) { for (int j = tid; j < k && j < B; j += T) s_label[j] = -1; }
    __syncthreads();

    const int l0e = s_label[0];
    lm = INF_I;
    for (int j = tid; j < B; j += T) {
        int l = s_label[j];
        atomicMin(&s_first[l + 1], j);
        if (l != l0e && j < lm) lm = j;
    }
    if (lm != INF_I) atomicMin(&s_fd_eff, lm);
    __syncthreads();

    for (int j = tid; j < B; j += T) {
        int l = s_label[j];
        if (j != s_first[l + 1]) atomicMin(&s_second[l + 1], j);
    }
    __syncthreads();

    const int fd = s_fd_eff;
    for (int i = tid; i < B; i += T) {
        int l  = s_label[i];
        int fo = s_first[l + 1];
        int myidx = zidx[i];
        int pos; bool vp;
        if (zidx[fo] != myidx) { pos = fo; vp = true; }
        else {
            int so = s_second[l + 1];
            if (so != INF_I) { pos = so; vp = true; }
            else             { pos = 0;  vp = false; }
        }
        int neg; bool vn;
        if (l != l0e)        { neg = 0;  vn = true; }
        else if (fd != INF_I){ neg = fd; vn = true; }
        else                 { neg = 0;  vn = false; }
        g_pos[i] = pos; g_neg[i] = neg; g_valid[i] = (vp && vn) ? 1 : 0;
    }
}

// -------- Kernel 2: distances, one WAVE per row, per-block partials --------
// No contended atomics: block writes g_bsum[bid]/g_bcnt[bid] (uncontended).
__global__ __launch_bounds__(256) void dist_kernel(
    const float* __restrict__ z, const int* __restrict__ g_pos,
    const int* __restrict__ g_neg, const int* __restrict__ g_valid,
    int B, int C, float* __restrict__ g_bsum, float* __restrict__ g_bcnt)
{
    const int wave = threadIdx.x >> 6;
    const int lane = threadIdx.x & 63;
    const int wpb  = blockDim.x >> 6;                 // waves per block (4)
    const int gwave  = blockIdx.x * wpb + wave;
    const int nwaves = gridDim.x * wpb;

    float lsum = 0.f, lcnt = 0.f;
    for (int i = gwave; i < B; i += nwaves) {
        const float* a = z + (size_t)i * C;
        const float* p = z + (size_t)g_pos[i] * C;
        const float* n = z + (size_t)g_neg[i] * C;
        float sap = 0.f, san = 0.f;
        const int nk = C >> 8;                        // C / (64 lanes * 4)
        for (int k = 0; k < nk; ++k) {
            int c = ((k << 6) + lane) << 2;           // coalesced float4
            float4 av = *(const float4*)(a + c);
            float4 pv = *(const float4*)(p + c);
            float4 nv = *(const float4*)(n + c);
            float d;
            d = av.x - pv.x + EPSC; sap += d * d;
            d = av.y - pv.y + EPSC; sap += d * d;
            d = av.z - pv.z + EPSC; sap += d * d;
            d = av.w - pv.w + EPSC; sap += d * d;
            d = av.x - nv.x + EPSC; san += d * d;
            d = av.y - nv.y + EPSC; san += d * d;
            d = av.z - nv.z + EPSC; san += d * d;
            d = av.w - nv.w + EPSC; san += d * d;
        }
        for (int off = 32; off; off >>= 1) {
            sap += __shfl_xor(sap, off, 64);
            san += __shfl_xor(san, off, 64);
        }
        if (lane == 0 && g_valid[i]) {
            lsum += fmaxf(sqrtf(sap) - sqrtf(san) + MARGIN, 0.f);
            lcnt += 1.f;
        }
    }

    __shared__ float s_sum[4], s_cnt[4];
    if (lane == 0) { s_sum[wave] = lsum; s_cnt[wave] = lcnt; }
    __syncthreads();
    if (threadIdx.x == 0) {
        float bs = 0.f, bc = 0.f;
        for (int w = 0; w < wpb; ++w) { bs += s_sum[w]; bc += s_cnt[w]; }
        g_bsum[blockIdx.x] = bs;
        g_bcnt[blockIdx.x] = bc;
    }
}

// -------- Kernel 3: reduce NB partials, write loss --------
__global__ __launch_bounds__(256) void final_kernel(
    const float* __restrict__ g_bsum, const float* __restrict__ g_bcnt,
    int nb, float* __restrict__ out)
{
    const int t = threadIdx.x;
    float s = 0.f, c = 0.f;
    for (int i = t; i < nb; i += blockDim.x) { s += g_bsum[i]; c += g_bcnt[i]; }
    for (int off = 32; off; off >>= 1) {
        s += __shfl_xor(s, off, 64);
        c += __shfl_xor(c, off, 64);
    }
    __shared__ float s_s[4], s_c[4];
    const int wave = t >> 6, lane = t & 63;
    if (lane == 0) { s_s[wave] = s; s_c[wave] = c; }
    __syncthreads();
    if (t == 0) {
        float ts = 0.f, tc = 0.f;
        for (int w = 0; w < 4; ++w) { ts += s_s[w]; tc += s_c[w]; }
        out[0] = (tc > 0.f) ? ts / tc : 0.f;
    }
}

extern "C" void kernel_launch(void* const* d_in, const int* in_sizes, int n_in,
                              void* d_out, int out_size, void* d_ws, size_t ws_size,
                              hipStream_t stream) {
    const int*   z_label = (const int*)d_in[0];
    const int*   z_idx   = (const int*)d_in[1];
    const float* z       = (const float*)d_in[2];
    const int B = in_sizes[0];
    const int C = in_sizes[2] / B;
    float* out = (float*)d_out;

    char* base = (char*)d_ws;
    float* g_bsum = (float*)base;
    float* g_bcnt = g_bsum + NB;
    int*   g_pos   = (int*)(g_bcnt + NB);
    int*   g_neg   = g_pos + B;
    int*   g_valid = g_neg + B;

    mine_kernel<<<1, 1024, 0, stream>>>(z_label, z_idx, B, g_pos, g_neg, g_valid);
    dist_kernel<<<NB, 256, 0, stream>>>(z, g_pos, g_neg, g_valid, B, C,
                                        g_bsum, g_bcnt);
    final_kernel<<<1, 256, 0, stream>>>(g_bsum, g_bcnt, NB, out);
}

// Round 3
// 97.106 us; speedup vs baseline: 4.0151x; 1.0186x over previous
//
#include <hip/hip_runtime.h>

#define MARGIN 0.2f
#define EPSC 1e-6f
#define INF_I 0x7fffffff

// -------- Kernel 1: triplet mining (single block) --------
// first/second-occurrence tables per label instead of the B x B mask.
__global__ __launch_bounds__(1024) void mine_kernel(
    const int* __restrict__ label, const int* __restrict__ zidx, int B,
    int* __restrict__ g_pos, int* __restrict__ g_neg, int* __restrict__ g_valid)
{
    __shared__ int s_label[8192];        // B <= 8192
    __shared__ int s_first[258];         // labels in [-1, 256] -> index l+1
    __shared__ int s_second[258];
    __shared__ int s_fd_orig;            // first j with label[j] != label[0] (orig)
    __shared__ int s_fd_eff;             // same, effective labels
    const int tid = threadIdx.x;
    const int T   = blockDim.x;

    if (tid < 258) { s_first[tid] = INF_I; s_second[tid] = INF_I; }
    if (tid == 0) { s_fd_orig = INF_I; s_fd_eff = INF_I; }
    if ((B & 3) == 0) {
        for (int j = tid * 4; j < B; j += T * 4) {
            int4 v = *(const int4*)(label + j);
            s_label[j] = v.x; s_label[j+1] = v.y; s_label[j+2] = v.z; s_label[j+3] = v.w;
        }
    } else {
        for (int j = tid; j < B; j += T) s_label[j] = label[j];
    }
    __syncthreads();

    const int l0 = s_label[0];
    int lm = INF_I;
    for (int j = tid; j < B; j += T) { if (s_label[j] != l0) { lm = j; break; } }
    if (lm != INF_I) atomicMin(&s_fd_orig, lm);
    __syncthreads();

    const bool all_same = (s_fd_orig == INF_I);
    int k = B / 100; if (k < 2) k = 2;
    if (all_same) { for (int j = tid; j < k && j < B; j += T) s_label[j] = -1; }
    __syncthreads();

    const int l0e = s_label[0];
    lm = INF_I;
    for (int j = tid; j < B; j += T) {
        int l = s_label[j];
        atomicMin(&s_first[l + 1], j);
        if (l != l0e && j < lm) lm = j;
    }
    if (lm != INF_I) atomicMin(&s_fd_eff, lm);
    __syncthreads();

    for (int j = tid; j < B; j += T) {
        int l = s_label[j];
        if (j != s_first[l + 1]) atomicMin(&s_second[l + 1], j);
    }
    __syncthreads();

    const int fd = s_fd_eff;
    for (int i = tid; i < B; i += T) {
        int l  = s_label[i];
        int fo = s_first[l + 1];
        int myidx = zidx[i];
        int pos; bool vp;
        if (zidx[fo] != myidx) { pos = fo; vp = true; }
        else {
            int so = s_second[l + 1];
            if (so != INF_I) { pos = so; vp = true; }
            else             { pos = 0;  vp = false; }
        }
        int neg; bool vn;
        if (l != l0e)        { neg = 0;  vn = true; }
        else if (fd != INF_I){ neg = fd; vn = true; }
        else                 { neg = 0;  vn = false; }
        g_pos[i] = pos; g_neg[i] = neg; g_valid[i] = (vp && vn) ? 1 : 0;
    }
}

__device__ inline void acc8(const float4& av, const float4& pv, const float4& nv,
                            float& sap, float& san) {
    float d;
    d = av.x - pv.x + EPSC; sap += d * d;
    d = av.y - pv.y + EPSC; sap += d * d;
    d = av.z - pv.z + EPSC; sap += d * d;
    d = av.w - pv.w + EPSC; sap += d * d;
    d = av.x - nv.x + EPSC; san += d * d;
    d = av.y - nv.y + EPSC; san += d * d;
    d = av.z - nv.z + EPSC; san += d * d;
    d = av.w - nv.w + EPSC; san += d * d;
}

// -------- Kernel 2: distances, ONE wave per row, per-block partials --------
// grid = ceil(B/4) blocks x 256 threads; no contended atomics anywhere.
__global__ __launch_bounds__(256) void dist_kernel(
    const float* __restrict__ z, const int* __restrict__ g_pos,
    const int* __restrict__ g_neg, const int* __restrict__ g_valid,
    int B, int C, float* __restrict__ g_bsum, float* __restrict__ g_bcnt)
{
    const int wave = threadIdx.x >> 6;
    const int lane = threadIdx.x & 63;
    const int i = blockIdx.x * 4 + wave;

    float lsum = 0.f, lcnt = 0.f;
    if (i < B) {
        const float4* a = (const float4*)(z + (size_t)i * C) + lane;
        const float4* p = (const float4*)(z + (size_t)g_pos[i] * C) + lane;
        const float4* n = (const float4*)(z + (size_t)g_neg[i] * C) + lane;
        float sap = 0.f, san = 0.f;
        if (C == 1024) {
            // issue all 12 loads before any use -> max MLP
            float4 a0 = a[0], a1 = a[64], a2 = a[128], a3 = a[192];
            float4 p0 = p[0], p1 = p[64], p2 = p[128], p3 = p[192];
            float4 n0 = n[0], n1 = n[64], n2 = n[128], n3 = n[192];
            acc8(a0, p0, n0, sap, san);
            acc8(a1, p1, n1, sap, san);
            acc8(a2, p2, n2, sap, san);
            acc8(a3, p3, n3, sap, san);
        } else {
            const int nk = C >> 8;
            for (int k = 0; k < nk; ++k)
                acc8(a[k * 64], p[k * 64], n[k * 64], sap, san);
            // ragged tail (C not multiple of 256): scalar
            for (int c = (nk << 8) + lane; c < C; c += 64) {
                float av = z[(size_t)i * C + c];
                float pv = z[(size_t)g_pos[i] * C + c];
                float nv = z[(size_t)g_neg[i] * C + c];
                float d = av - pv + EPSC; sap += d * d;
                d = av - nv + EPSC; san += d * d;
            }
        }
        for (int off = 32; off; off >>= 1) {
            sap += __shfl_xor(sap, off, 64);
            san += __shfl_xor(san, off, 64);
        }
        if (lane == 0 && g_valid[i]) {
            lsum = fmaxf(sqrtf(sap) - sqrtf(san) + MARGIN, 0.f);
            lcnt = 1.f;
        }
    }

    __shared__ float s_sum[4], s_cnt[4];
    if (lane == 0) { s_sum[wave] = lsum; s_cnt[wave] = lcnt; }
    __syncthreads();
    if (threadIdx.x == 0) {
        float bs = 0.f, bc = 0.f;
        for (int w = 0; w < 4; ++w) { bs += s_sum[w]; bc += s_cnt[w]; }
        g_bsum[blockIdx.x] = bs;   // unconditional: no ws-init needed
        g_bcnt[blockIdx.x] = bc;
    }
}

// -------- Kernel 3: reduce partials, write loss --------
__global__ __launch_bounds__(256) void final_kernel(
    const float* __restrict__ g_bsum, const float* __restrict__ g_bcnt,
    int nb, float* __restrict__ out)
{
    const int t = threadIdx.x;
    float s = 0.f, c = 0.f;
    for (int i = t; i < nb; i += blockDim.x) { s += g_bsum[i]; c += g_bcnt[i]; }
    for (int off = 32; off; off >>= 1) {
        s += __shfl_xor(s, off, 64);
        c += __shfl_xor(c, off, 64);
    }
    __shared__ float s_s[4], s_c[4];
    const int wave = t >> 6, lane = t & 63;
    if (lane == 0) { s_s[wave] = s; s_c[wave] = c; }
    __syncthreads();
    if (t == 0) {
        float ts = 0.f, tc = 0.f;
        for (int w = 0; w < 4; ++w) { ts += s_s[w]; tc += s_c[w]; }
        out[0] = (tc > 0.f) ? ts / tc : 0.f;
    }
}

extern "C" void kernel_launch(void* const* d_in, const int* in_sizes, int n_in,
                              void* d_out, int out_size, void* d_ws, size_t ws_size,
                              hipStream_t stream) {
    const int*   z_label = (const int*)d_in[0];
    const int*   z_idx   = (const int*)d_in[1];
    const float* z       = (const float*)d_in[2];
    const int B = in_sizes[0];
    const int C = in_sizes[2] / B;
    float* out = (float*)d_out;

    const int nblk = (B + 3) / 4;       // one wave per row, 4 waves/block

    char* base = (char*)d_ws;
    float* g_bsum = (float*)base;
    float* g_bcnt = g_bsum + nblk;
    int*   g_pos   = (int*)(g_bcnt + nblk);
    int*   g_neg   = g_pos + B;
    int*   g_valid = g_neg + B;

    mine_kernel<<<1, 1024, 0, stream>>>(z_label, z_idx, B, g_pos, g_neg, g_valid);
    dist_kernel<<<nblk, 256, 0, stream>>>(z, g_pos, g_neg, g_valid, B, C,
                                          g_bsum, g_bcnt);
    final_kernel<<<1, 256, 0, stream>>>(g_bsum, g_bcnt, nblk, out);
}

// Round 4
// 89.346 us; speedup vs baseline: 4.3639x; 1.0869x over previous
//
#include <hip/hip_runtime.h>

#define MARGIN 0.2f
#define EPSC 1e-6f

__device__ inline void acc8(const float4& av, const float4& pv, const float4& nv,
                            float& sap, float& san) {
    float d;
    d = av.x - pv.x + EPSC; sap += d * d;
    d = av.y - pv.y + EPSC; sap += d * d;
    d = av.z - pv.z + EPSC; sap += d * d;
    d = av.w - pv.w + EPSC; sap += d * d;
    d = av.x - nv.x + EPSC; san += d * d;
    d = av.y - nv.y + EPSC; san += d * d;
    d = av.z - nv.z + EPSC; san += d * d;
    d = av.w - nv.w + EPSC; san += d * d;
}

// -------- Kernel 1: fused mining + distances, ONE wave per row --------
// Mining is a per-wave ballot scan over the label array (L1/L2-resident):
//   pos = first j with label[j]==label[i] && zidx[j]!=zidx[i]  (expected j ~ 32)
//   neg = first j with label[j]!=label[i]                      (expected j ~ 1)
// Early-exit when both found. If the full scan finds NO different label, all
// labels are identical -> reference relabels rows [0,k) to -1; re-scan with
// those effective labels (cold path, analytic relabel, no global pass needed).
__global__ __launch_bounds__(256) void dist_kernel(
    const float* __restrict__ z, const int* __restrict__ label,
    const int* __restrict__ zidx, int B, int C, float2* __restrict__ g_part)
{
    const int wave = threadIdx.x >> 6;
    const int lane = threadIdx.x & 63;
    const int i = blockIdx.x * 4 + wave;

    float lsum = 0.f, lcnt = 0.f;
    if (i < B) {
        const int li    = label[i];
        const int myidx = zidx[i];

        // preload anchor before the scan to overlap VMEM latency
        const float4* a = (const float4*)(z + (size_t)i * C) + lane;
        float4 a0, a1, a2, a3;
        const bool c1024 = (C == 1024);
        if (c1024) { a0 = a[0]; a1 = a[64]; a2 = a[128]; a3 = a[192]; }

        int pos = -1, neg = -1;
        for (int j0 = 0; j0 < B && (pos < 0 || neg < 0); j0 += 64) {
            const int j = j0 + lane;
            const bool inb = j < B;
            int lj = 0, xj = 0;
            if (inb) { lj = label[j]; xj = zidx[j]; }
            unsigned long long pb = __ballot(inb && lj == li && xj != myidx);
            unsigned long long nb = __ballot(inb && lj != li);
            if (pos < 0 && pb) pos = j0 + (__ffsll((unsigned long long)pb) - 1);
            if (neg < 0 && nb) neg = j0 + (__ffsll((unsigned long long)nb) - 1);
        }
        if (neg < 0) {
            // all labels identical: effective labels are -1 for j<k, l0 else
            int k = B / 100; if (k < 2) k = 2;
            const int l0  = li;
            const int lie = (i < k) ? -1 : l0;
            pos = -1; neg = -1;
            for (int j0 = 0; j0 < B && (pos < 0 || neg < 0); j0 += 64) {
                const int j = j0 + lane;
                const bool inb = j < B;
                int xj = 0;
                if (inb) xj = zidx[j];
                const int lje = (j < k) ? -1 : l0;
                unsigned long long pb = __ballot(inb && lje == lie && xj != myidx);
                unsigned long long nb = __ballot(inb && lje != lie);
                if (pos < 0 && pb) pos = j0 + (__ffsll((unsigned long long)pb) - 1);
                if (neg < 0 && nb) neg = j0 + (__ffsll((unsigned long long)nb) - 1);
            }
        }
        const bool valid = (pos >= 0) && (neg >= 0);
        const int pi = pos < 0 ? 0 : pos;    // argmax of all-False row = 0
        const int ni = neg < 0 ? 0 : neg;

        const float4* p = (const float4*)(z + (size_t)pi * C) + lane;
        const float4* n = (const float4*)(z + (size_t)ni * C) + lane;
        float sap = 0.f, san = 0.f;
        if (c1024) {
            float4 p0 = p[0], p1 = p[64], p2 = p[128], p3 = p[192];
            float4 n0 = n[0], n1 = n[64], n2 = n[128], n3 = n[192];
            acc8(a0, p0, n0, sap, san);
            acc8(a1, p1, n1, sap, san);
            acc8(a2, p2, n2, sap, san);
            acc8(a3, p3, n3, sap, san);
        } else {
            const int nk = C >> 8;
            for (int kk = 0; kk < nk; ++kk)
                acc8(a[kk * 64], p[kk * 64], n[kk * 64], sap, san);
            for (int c = (nk << 8) + lane; c < C; c += 64) {
                float av = z[(size_t)i * C + c];
                float pv = z[(size_t)pi * C + c];
                float nv = z[(size_t)ni * C + c];
                float d = av - pv + EPSC; sap += d * d;
                d = av - nv + EPSC; san += d * d;
            }
        }
        for (int off = 32; off; off >>= 1) {
            sap += __shfl_xor(sap, off, 64);
            san += __shfl_xor(san, off, 64);
        }
        if (lane == 0 && valid) {
            lsum = fmaxf(sqrtf(sap) - sqrtf(san) + MARGIN, 0.f);
            lcnt = 1.f;
        }
    }

    __shared__ float s_sum[4], s_cnt[4];
    if (lane == 0) { s_sum[wave] = lsum; s_cnt[wave] = lcnt; }
    __syncthreads();
    if (threadIdx.x == 0) {
        float bs = 0.f, bc = 0.f;
        for (int w = 0; w < 4; ++w) { bs += s_sum[w]; bc += s_cnt[w]; }
        g_part[blockIdx.x] = make_float2(bs, bc);   // uncontended, no ws-init needed
    }
}

// -------- Kernel 2: reduce partials, write loss --------
__global__ __launch_bounds__(1024) void final_kernel(
    const float2* __restrict__ g_part, int nb, float* __restrict__ out)
{
    const int t = threadIdx.x;
    float s = 0.f, c = 0.f;
    for (int idx = t; idx < nb; idx += blockDim.x) {
        float2 v = g_part[idx];
        s += v.x; c += v.y;
    }
    for (int off = 32; off; off >>= 1) {
        s += __shfl_xor(s, off, 64);
        c += __shfl_xor(c, off, 64);
    }
    __shared__ float s_s[16], s_c[16];
    const int wave = t >> 6, lane = t & 63;
    if (lane == 0) { s_s[wave] = s; s_c[wave] = c; }
    __syncthreads();
    if (t == 0) {
        float ts = 0.f, tc = 0.f;
        const int nw = blockDim.x >> 6;
        for (int w = 0; w < nw; ++w) { ts += s_s[w]; tc += s_c[w]; }
        out[0] = (tc > 0.f) ? ts / tc : 0.f;
    }
}

extern "C" void kernel_launch(void* const* d_in, const int* in_sizes, int n_in,
                              void* d_out, int out_size, void* d_ws, size_t ws_size,
                              hipStream_t stream) {
    const int*   z_label = (const int*)d_in[0];
    const int*   z_idx   = (const int*)d_in[1];
    const float* z       = (const float*)d_in[2];
    const int B = in_sizes[0];
    const int C = in_sizes[2] / B;
    float* out = (float*)d_out;

    const int nblk = (B + 3) / 4;       // one wave per row, 4 waves/block
    float2* g_part = (float2*)d_ws;

    dist_kernel<<<nblk, 256, 0, stream>>>(z, z_label, z_idx, B, C, g_part);
    final_kernel<<<1, 1024, 0, stream>>>(g_part, nblk, out);
}

// Round 5
// 85.089 us; speedup vs baseline: 4.5822x; 1.0500x over previous
//
#include <hip/hip_runtime.h>

#define MARGIN 0.2f
#define EPSC 1e-6f

__device__ inline void acc8(const float4& av, const float4& pv, const float4& nv,
                            float& sap, float& san) {
    float d;
    d = av.x - pv.x + EPSC; sap += d * d;
    d = av.y - pv.y + EPSC; sap += d * d;
    d = av.z - pv.z + EPSC; sap += d * d;
    d = av.w - pv.w + EPSC; sap += d * d;
    d = av.x - nv.x + EPSC; san += d * d;
    d = av.y - nv.y + EPSC; san += d * d;
    d = av.z - nv.z + EPSC; san += d * d;
    d = av.w - nv.w + EPSC; san += d * d;
}

// One 256-wide scan step: lane holds j = j0 + lane*4 + s (s=0..3).
// Updates pos/neg (first-j semantics) for one row's (li, myidx).
__device__ inline void scan4(const int4& lj, const int4& xj, int li, int myidx,
                             int j0, int& pos, int& neg) {
    if (pos < 0) {
        int m = ((lj.x == li && xj.x != myidx) ? 1 : 0)
              | ((lj.y == li && xj.y != myidx) ? 2 : 0)
              | ((lj.z == li && xj.z != myidx) ? 4 : 0)
              | ((lj.w == li && xj.w != myidx) ? 8 : 0);
        unsigned long long b = __ballot(m != 0);
        if (b) {
            int L  = __ffsll(b) - 1;
            int mL = __shfl(m, L, 64);
            pos = j0 + L * 4 + (__ffs(mL) - 1);
        }
    }
    if (neg < 0) {
        int m = ((lj.x != li) ? 1 : 0) | ((lj.y != li) ? 2 : 0)
              | ((lj.z != li) ? 4 : 0) | ((lj.w != li) ? 8 : 0);
        unsigned long long b = __ballot(m != 0);
        if (b) {
            int L  = __ffsll(b) - 1;
            int mL = __shfl(m, L, 64);
            neg = j0 + L * 4 + (__ffs(mL) - 1);
        }
    }
}

// Generic 64-wide per-row scan (B not a multiple of 256).
__device__ inline void mine_row_64(const int* __restrict__ label,
                                   const int* __restrict__ zidx, int B, int lane,
                                   int li, int myidx, int& pos, int& neg) {
    pos = -1; neg = -1;
    for (int j0 = 0; j0 < B && (pos < 0 || neg < 0); j0 += 64) {
        int j = j0 + lane;
        bool inb = j < B;
        int lj = 0, xj = 0;
        if (inb) { lj = label[j]; xj = zidx[j]; }
        unsigned long long pb = __ballot(inb && lj == li && xj != myidx);
        unsigned long long nb = __ballot(inb && lj != li);
        if (pos < 0 && pb) pos = j0 + __ffsll(pb) - 1;
        if (neg < 0 && nb) neg = j0 + __ffsll(nb) - 1;
    }
}

// Cold path: ALL labels identical -> reference relabels rows [0,k) to -1.
// Effective-label structure is analytic: groups are [0,k) and [k,B).
// neg = first j in the OTHER group (k or 0); pos = first j in OWN group with
// zidx[j] != myidx. pos/neg stay -1 when the respective mask has no True.
__device__ inline void mine_allsame(const int* __restrict__ zidx, int B, int lane,
                                    int i, int myidx, int& pos, int& neg) {
    int k = B / 100; if (k < 2) k = 2;
    int kk = k < B ? k : B;
    int lo, hi;
    if (i < kk) { lo = 0;  hi = kk; neg = (kk < B) ? kk : -1; }
    else        { lo = kk; hi = B;  neg = 0; }
    pos = -1;
    for (int j0 = lo; j0 < hi && pos < 0; j0 += 64) {
        int j = j0 + lane;
        bool ok = (j < hi) && (zidx[j] != myidx);
        unsigned long long b = __ballot(ok);
        if (b) pos = j0 + __ffsll(b) - 1;
    }
}

// -------- Kernel 1: fused mining + distances, TWO rows per wave --------
// grid = ceil(B/8) blocks x 256 threads (4 waves). Each wave mines + reduces
// rows ia, ia+1 sharing the int4 label/zidx chunk loads (256 j per step).
// No contended atomics; per-block float2 partials.
__global__ __launch_bounds__(256) void dist_kernel(
    const float* __restrict__ z, const int* __restrict__ label,
    const int* __restrict__ zidx, int B, int C, float2* __restrict__ g_part)
{
    const int wave = threadIdx.x >> 6;
    const int lane = threadIdx.x & 63;
    const int ia = blockIdx.x * 8 + wave * 2;
    const int ib = ia + 1;
    const bool hasA = ia < B, hasB = ib < B;
    const bool c1024 = (C == 1024);

    float lsum = 0.f, lcnt = 0.f;

    int liA = 0, idxA = 0, liB = 0, idxB = 0;
    if (hasA) { liA = label[ia]; idxA = zidx[ia]; }
    if (hasB) { liB = label[ib]; idxB = zidx[ib]; }

    // preload both anchors; these stay in flight across the mining scan
    const float4* aA = (const float4*)(z + (size_t)ia * C) + lane;
    const float4* aB = (const float4*)(z + (size_t)ib * C) + lane;
    float4 A0, A1, A2, A3, Bb0, Bb1, Bb2, Bb3;
    if (hasA && c1024) { A0 = aA[0]; A1 = aA[64]; A2 = aA[128]; A3 = aA[192]; }
    if (hasB && c1024) { Bb0 = aB[0]; Bb1 = aB[64]; Bb2 = aB[128]; Bb3 = aB[192]; }

    int posA = -1, negA = -1, posB = -1, negB = -1;
    if (hasA) {
        if ((B & 255) == 0) {
            if (!hasB) { posB = 0; negB = 0; }       // sentinel: already "found"
            for (int j0 = 0; j0 < B && (posA < 0 || negA < 0 || posB < 0 || negB < 0);
                 j0 += 256) {
                const int base = j0 + lane * 4;
                int4 lj = *(const int4*)(label + base);
                int4 xj = *(const int4*)(zidx + base);
                scan4(lj, xj, liA, idxA, j0, posA, negA);
                if (hasB) scan4(lj, xj, liB, idxB, j0, posB, negB);
            }
        } else {
            mine_row_64(label, zidx, B, lane, liA, idxA, posA, negA);
            if (hasB) mine_row_64(label, zidx, B, lane, liB, idxB, posB, negB);
        }
        if (negA < 0) {  // no different label anywhere -> all-same cold path
            mine_allsame(zidx, B, lane, ia, idxA, posA, negA);
            if (hasB) mine_allsame(zidx, B, lane, ib, idxB, posB, negB);
        }
    }

    // ---- row A distances ----
    if (hasA) {
        const int pi = posA < 0 ? 0 : posA;          // argmax of all-False = 0
        const int ni = negA < 0 ? 0 : negA;
        const float4* p = (const float4*)(z + (size_t)pi * C) + lane;
        const float4* n = (const float4*)(z + (size_t)ni * C) + lane;
        float sap = 0.f, san = 0.f;
        if (c1024) {
            float4 p0 = p[0], p1 = p[64], p2 = p[128], p3 = p[192];
            float4 n0 = n[0], n1 = n[64], n2 = n[128], n3 = n[192];
            acc8(A0, p0, n0, sap, san); acc8(A1, p1, n1, sap, san);
            acc8(A2, p2, n2, sap, san); acc8(A3, p3, n3, sap, san);
        } else {
            const float4* a = (const float4*)(z + (size_t)ia * C) + lane;
            const int nk = C >> 8;
            for (int kk = 0; kk < nk; ++kk)
                acc8(a[kk * 64], p[kk * 64], n[kk * 64], sap, san);
            for (int c = (nk << 8) + lane; c < C; c += 64) {
                float av = z[(size_t)ia * C + c];
                float pv = z[(size_t)pi * C + c];
                float nv = z[(size_t)ni * C + c];
                float d = av - pv + EPSC; sap += d * d;
                d = av - nv + EPSC; san += d * d;
            }
        }
        for (int off = 32; off; off >>= 1) {
            sap += __shfl_xor(sap, off, 64);
            san += __shfl_xor(san, off, 64);
        }
        if (lane == 0 && posA >= 0 && negA >= 0) {
            lsum += fmaxf(sqrtf(sap) - sqrtf(san) + MARGIN, 0.f);
            lcnt += 1.f;
        }
    }

    // ---- row B distances ----
    if (hasB) {
        const int pi = posB < 0 ? 0 : posB;
        const int ni = negB < 0 ? 0 : negB;
        const float4* p = (const float4*)(z + (size_t)pi * C) + lane;
        const float4* n = (const float4*)(z + (size_t)ni * C) + lane;
        float sap = 0.f, san = 0.f;
        if (c1024) {
            float4 p0 = p[0], p1 = p[64], p2 = p[128], p3 = p[192];
            float4 n0 = n[0], n1 = n[64], n2 = n[128], n3 = n[192];
            acc8(Bb0, p0, n0, sap, san); acc8(Bb1, p1, n1, sap, san);
            acc8(Bb2, p2, n2, sap, san); acc8(Bb3, p3, n3, sap, san);
        } else {
            const float4* a = (const float4*)(z + (size_t)ib * C) + lane;
            const int nk = C >> 8;
            for (int kk = 0; kk < nk; ++kk)
                acc8(a[kk * 64], p[kk * 64], n[kk * 64], sap, san);
            for (int c = (nk << 8) + lane; c < C; c += 64) {
                float av = z[(size_t)ib * C + c];
                float pv = z[(size_t)pi * C + c];
                float nv = z[(size_t)ni * C + c];
                float d = av - pv + EPSC; sap += d * d;
                d = av - nv + EPSC; san += d * d;
            }
        }
        for (int off = 32; off; off >>= 1) {
            sap += __shfl_xor(sap, off, 64);
            san += __shfl_xor(san, off, 64);
        }
        if (lane == 0 && posB >= 0 && negB >= 0) {
            lsum += fmaxf(sqrtf(sap) - sqrtf(san) + MARGIN, 0.f);
            lcnt += 1.f;
        }
    }

    __shared__ float s_sum[4], s_cnt[4];
    if (lane == 0) { s_sum[wave] = lsum; s_cnt[wave] = lcnt; }
    __syncthreads();
    if (threadIdx.x == 0) {
        float bs = 0.f, bc = 0.f;
        for (int w = 0; w < 4; ++w) { bs += s_sum[w]; bc += s_cnt[w]; }
        g_part[blockIdx.x] = make_float2(bs, bc);   // uncontended, no ws-init needed
    }
}

// -------- Kernel 2: reduce partials, write loss --------
__global__ __launch_bounds__(1024) void final_kernel(
    const float2* __restrict__ g_part, int nb, float* __restrict__ out)
{
    const int t = threadIdx.x;
    float s = 0.f, c = 0.f;
    for (int idx = t; idx < nb; idx += blockDim.x) {
        float2 v = g_part[idx];
        s += v.x; c += v.y;
    }
    for (int off = 32; off; off >>= 1) {
        s += __shfl_xor(s, off, 64);
        c += __shfl_xor(c, off, 64);
    }
    __shared__ float s_s[16], s_c[16];
    const int wave = t >> 6, lane = t & 63;
    if (lane == 0) { s_s[wave] = s; s_c[wave] = c; }
    __syncthreads();
    if (t == 0) {
        float ts = 0.f, tc = 0.f;
        const int nw = blockDim.x >> 6;
        for (int w = 0; w < nw; ++w) { ts += s_s[w]; tc += s_c[w]; }
        out[0] = (tc > 0.f) ? ts / tc : 0.f;
    }
}

extern "C" void kernel_launch(void* const* d_in, const int* in_sizes, int n_in,
                              void* d_out, int out_size, void* d_ws, size_t ws_size,
                              hipStream_t stream) {
    const int*   z_label = (const int*)d_in[0];
    const int*   z_idx   = (const int*)d_in[1];
    const float* z       = (const float*)d_in[2];
    const int B = in_sizes[0];
    const int C = in_sizes[2] / B;
    float* out = (float*)d_out;

    const int nblk = (B + 7) / 8;       // 2 rows per wave, 4 waves/block
    float2* g_part = (float2*)d_ws;

    dist_kernel<<<nblk, 256, 0, stream>>>(z, z_label, z_idx, B, C, g_part);
    final_kernel<<<1, 1024, 0, stream>>>(g_part, nblk, out);
}